// Round 16
// baseline (343.733 us; speedup 1.0000x reference)
//
#include <hip/hip_runtime.h>
#include <hip/hip_bf16.h>

// ---------------- problem constants ----------------
#define T_    8192
#define INDIM 1024
#define MTR   64
#define CCTX  16
#define MC    1024     // MTR*CCTX
#define NOUT  1024
#define CHUNK 64
#define NCH   128      // T_/CHUNK

using bf16x8 = __attribute__((ext_vector_type(8))) short;
using f32x4  = __attribute__((ext_vector_type(4))) float;

__device__ __forceinline__ unsigned short f2bf(float f) {
  unsigned int u = __builtin_bit_cast(unsigned int, f);
  u += 0x7fffu + ((u >> 16) & 1u);
  return (unsigned short)(u >> 16);
}
__device__ __forceinline__ float bf2f(unsigned short u) {
  return __builtin_bit_cast(float, (unsigned int)u << 16);
}

// cheap mish: v * tanh(softplus(v)) = v * w/(w+2), w = e^v*(e^v+2); v>20 -> v
__device__ __forceinline__ float mish_f(float v) {
  float u = __expf(v);
  float w = u * (u + 2.f);
  return (v > 20.f) ? v : v * __fdividef(w, w + 2.f);
}

typedef __attribute__((address_space(1))) void gas_void;
typedef __attribute__((address_space(3))) void las_void;

__device__ __forceinline__ void gload_lds16(const void* g, void* l) {
  __builtin_amdgcn_global_load_lds((gas_void*)g, (las_void*)l, 16, 0, 0);
}

__device__ __forceinline__ float2 block_sum2(float s, float ss, float* sbuf) {
#pragma unroll
  for (int off = 32; off > 0; off >>= 1) {
    s  += __shfl_down(s, off);
    ss += __shfl_down(ss, off);
  }
  if ((threadIdx.x & 63) == 0) {
    sbuf[(threadIdx.x >> 6) * 2]     = s;
    sbuf[(threadIdx.x >> 6) * 2 + 1] = ss;
  }
  __syncthreads();
  return make_float2(sbuf[0] + sbuf[2] + sbuf[4] + sbuf[6],
                     sbuf[1] + sbuf[3] + sbuf[5] + sbuf[7]);
}

// ---------------- merged prep: weight casts | w1 row sums | LN stats + x cast ----------------
__global__ __launch_bounds__(256) void prep_k(const float* __restrict__ w1, const float* __restrict__ w2,
                                              const float* __restrict__ w3, const float* __restrict__ sw,
                                              const float* __restrict__ x,
                                              unsigned short* __restrict__ o1, unsigned short* __restrict__ o2,
                                              unsigned short* __restrict__ o3, unsigned short* __restrict__ o4,
                                              float* __restrict__ wre, float* __restrict__ wim,
                                              float2* __restrict__ rowstat, unsigned short* __restrict__ xb) {
  __shared__ float sbuf[8];
  const int b = blockIdx.x;
  if (b < 5120) {
    long i = ((long)b * 256 + threadIdx.x) * 4;
    const float* src; unsigned short* dst; long off;
    if (i < 2097152)      { src = w1; dst = o1; off = i; }
    else if (i < 3145728) { src = w2; dst = o2; off = i - 2097152; }
    else if (i < 4194304) { src = w3; dst = o3; off = i - 3145728; }
    else if (i < 5242880) { src = sw; dst = o4; off = i - 4194304; }
    else return;
    float4 v = *(const float4*)(src + off);
    ushort4 o = { f2bf(v.x), f2bf(v.y), f2bf(v.z), f2bf(v.w) };
    *(ushort4*)(dst + off) = o;
  } else if (b < 6144) {
    const long row = b - 5120;
    const float4* r4 = (const float4*)(w1 + row * 2048);
    float4 a = r4[threadIdx.x];
    float4 c = r4[256 + threadIdx.x];
    float2 t = block_sum2(a.x + a.y + a.z + a.w, c.x + c.y + c.z + c.w, sbuf);
    if (threadIdx.x == 0) { wre[row] = t.x; wim[row] = t.y; }
  } else {
    const long row = b - 6144;
    float4 v = ((const float4*)(x + (row << 10)))[threadIdx.x];
    ushort4 c = { f2bf(v.x), f2bf(v.y), f2bf(v.z), f2bf(v.w) };
    ((ushort4*)(xb + (row << 10)))[threadIdx.x] = c;
    float2 t = block_sum2(v.x + v.y + v.z + v.w,
                          v.x * v.x + v.y * v.y + v.z * v.z + v.w * v.w, sbuf);
    float mean = t.x * (1.f / 1024.f);
    float var  = t.y * (1.f / 1024.f) - mean * mean;
    float rstd = rsqrtf(var + 1e-5f);
    if (threadIdx.x == 0) rowstat[row] = make_float2(mean, rstd);
  }
}

// out = LN(h3) rows of 1024; h3 is bf16
__global__ __launch_bounds__(256) void ln_out1b_k(const unsigned short* __restrict__ p, float* __restrict__ out) {
  __shared__ float sbuf[8];
  const long row = blockIdx.x;
  ushort4 u4 = ((const ushort4*)(p + (row << 10)))[threadIdx.x];
  float4 v = { bf2f(u4.x), bf2f(u4.y), bf2f(u4.z), bf2f(u4.w) };
  float2 t = block_sum2(v.x + v.y + v.z + v.w,
                        v.x * v.x + v.y * v.y + v.z * v.z + v.w * v.w, sbuf);
  float mean = t.x * (1.f / 1024.f);
  float var  = t.y * (1.f / 1024.f) - mean * mean;
  float rstd = rsqrtf(var + 1e-5f);
  float4 o = { (v.x - mean) * rstd, (v.y - mean) * rstd,
               (v.z - mean) * rstd, (v.w - mean) * rstd };
  ((float4*)(out + (row << 10)))[threadIdx.x] = o;
}

// ---------------- f32 pre-projection: register-weights, LN applied algebraically (R12-proven) ----------------
__global__ __launch_bounds__(256) void pre_part_k(const float* __restrict__ x,
                                                  const float2* __restrict__ rowstat,
                                                  const float* __restrict__ pw,
                                                  float* __restrict__ part) {
  const int lane = threadIdx.x & 63;
  const int wvu  = __builtin_amdgcn_readfirstlane(threadIdx.x >> 6);
  const int kc   = blockIdx.y;
  const int r0   = (blockIdx.x * 4 + wvu) * 32;

  const float* wrow = pw + (long)lane * 1024 + kc * 128;
  float wreg[128];
#pragma unroll
  for (int j = 0; j < 32; ++j)
    *(float4*)&wreg[j * 4] = ((const float4*)wrow)[j];
  float swsum = 0.f;
#pragma unroll
  for (int j = 0; j < 128; ++j) swsum += wreg[j];

  float* po = part + ((long)kc * T_ + r0) * 64 + lane;
  const float* xbase = x + (long)r0 * 1024 + kc * 128;

  for (int i = 0; i < 32; i += 2) {
    const float4* xr0 = (const float4*)(xbase + (long)i * 1024);
    const float4* xr1 = (const float4*)(xbase + (long)(i + 1) * 1024);
    float a0 = 0.f, a1 = 0.f, a2 = 0.f, a3 = 0.f;
    float b0 = 0.f, b1 = 0.f, b2 = 0.f, b3 = 0.f;
#pragma unroll
    for (int j = 0; j < 32; j += 4) {
      float4 xa0 = xr0[j],     xa1 = xr0[j + 1], xa2 = xr0[j + 2], xa3 = xr0[j + 3];
      float4 xb0 = xr1[j],     xb1 = xr1[j + 1], xb2 = xr1[j + 2], xb3 = xr1[j + 3];
      a0 += wreg[4*j+0]*xa0.x  + wreg[4*j+1]*xa0.y  + wreg[4*j+2]*xa0.z  + wreg[4*j+3]*xa0.w;
      a1 += wreg[4*j+4]*xa1.x  + wreg[4*j+5]*xa1.y  + wreg[4*j+6]*xa1.z  + wreg[4*j+7]*xa1.w;
      a2 += wreg[4*j+8]*xa2.x  + wreg[4*j+9]*xa2.y  + wreg[4*j+10]*xa2.z + wreg[4*j+11]*xa2.w;
      a3 += wreg[4*j+12]*xa3.x + wreg[4*j+13]*xa3.y + wreg[4*j+14]*xa3.z + wreg[4*j+15]*xa3.w;
      b0 += wreg[4*j+0]*xb0.x  + wreg[4*j+1]*xb0.y  + wreg[4*j+2]*xb0.z  + wreg[4*j+3]*xb0.w;
      b1 += wreg[4*j+4]*xb1.x  + wreg[4*j+5]*xb1.y  + wreg[4*j+6]*xb1.z  + wreg[4*j+7]*xb1.w;
      b2 += wreg[4*j+8]*xb2.x  + wreg[4*j+9]*xb2.y  + wreg[4*j+10]*xb2.z + wreg[4*j+11]*xb2.w;
      b3 += wreg[4*j+12]*xb3.x + wreg[4*j+13]*xb3.y + wreg[4*j+14]*xb3.z + wreg[4*j+15]*xb3.w;
    }
    float2 s0 = rowstat[r0 + i];
    float2 s1 = rowstat[r0 + i + 1];
    po[(long)i * 64]       = s0.y * ((a0 + a1) + (a2 + a3)) - s0.x * s0.y * swsum;
    po[(long)(i + 1) * 64] = s1.y * ((b0 + b1) + (b2 + b3)) - s1.x * s1.y * swsum;
  }
}

// pre[t,m] = softplus(sum_kc part[kc][t][m] + pb[m])
__global__ __launch_bounds__(256) void pre_fin_k(const float* __restrict__ part,
                                                 const float* __restrict__ pb,
                                                 float* __restrict__ pre) {
  long i = (long)blockIdx.x * 256 + threadIdx.x;
  int m = (int)(i & 63);
  float s = 0.f;
#pragma unroll
  for (int kc = 0; kc < 8; ++kc)
    s += part[(long)kc * T_ * 64 + i];
  float v = s + pb[m];
  float sp = fmaxf(v, 0.f) + log1pf(expf(-fabsf(v)));
  pre[i] = sp;
}

// ---------------- chunked complex reset-scan (f64 internal) ----------------
__global__ __launch_bounds__(256) void scan_p1(const float* __restrict__ pre, const int* __restrict__ start,
                                               const float* __restrict__ a, const float* __restrict__ bfr,
                                               double2* __restrict__ chA, double2* __restrict__ chB) {
  int ch = blockIdx.y * 256 + threadIdx.x;
  int m = ch >> 4, c = ch & 15;
  double dec = exp(-fabs((double)a[m]));
  double th = (double)bfr[c];
  double gre = dec * cos(th), gim = dec * sin(th);
  int j = blockIdx.x;
  int t0 = j * CHUNK;
  double pr = 1.0, pi = 0.0, sr = 0.0, si = 0.0;
  for (int t = t0; t < t0 + CHUNK; ++t) {
    double b = (double)pre[(long)t * 64 + m];
    if (start[t]) {
      pr = 0.0; pi = 0.0; sr = b; si = 0.0;
    } else {
      double nsr = gre * sr - gim * si + b;
      si = gre * si + gim * sr; sr = nsr;
      double npr = gre * pr - gim * pi;
      pi = gre * pi + gim * pr; pr = npr;
    }
  }
  chA[j * MC + ch] = make_double2(pr, pi);
  chB[j * MC + ch] = make_double2(sr, si);
}

// composes chunks (16 blocks x 64 threads); writes carry + final-state tail.
__global__ __launch_bounds__(64) void scan_p2(const double2* __restrict__ chA, const double2* __restrict__ chB,
                                              const float* __restrict__ state0,
                                              double2* __restrict__ carry, double* __restrict__ red,
                                              float* __restrict__ out_tail, int fmt) {
  if (blockIdx.x == 0 && threadIdx.x < 4) red[threadIdx.x] = 0.0;
  int ch = blockIdx.x * 64 + threadIdx.x;
  double cr = (double)state0[ch], ci = 0.0;
  for (int j = 0; j < NCH; ++j) {
    carry[j * MC + ch] = make_double2(cr, ci);
    double2 A = chA[j * MC + ch];
    double2 B = chB[j * MC + ch];
    double ncr = A.x * cr - A.y * ci + B.x;
    ci = A.x * ci + A.y * cr + B.y;
    cr = ncr;
  }
  if (fmt == 1024) {
    out_tail[ch] = (float)cr;
  } else {
    out_tail[2 * ch]     = (float)cr;
    out_tail[2 * ch + 1] = (float)ci;
  }
}

// replay: reduction + RAW bf16 z write (normalization folded into mix1 epilogue)
__global__ __launch_bounds__(256) void scan_p3(const float* __restrict__ pre, const int* __restrict__ start,
                                               const float* __restrict__ a, const float* __restrict__ bfr,
                                               const double2* __restrict__ carry,
                                               double* __restrict__ red,
                                               unsigned short* __restrict__ z) {
  __shared__ double sbuf[12];
  int ch = blockIdx.y * 256 + threadIdx.x;
  int m = ch >> 4, c = ch & 15;
  double dec = exp(-fabs((double)a[m]));
  double th = (double)bfr[c];
  double gre = dec * cos(th), gim = dec * sin(th);
  int j = blockIdx.x;
  int t0 = j * CHUNK;
  double2 cin = carry[j * MC + ch];
  double sr = cin.x, si = cin.y;
  double aR = 0.0, aI = 0.0, aS = 0.0;
  for (int t = t0; t < t0 + CHUNK; ++t) {
    double b = (double)pre[(long)t * 64 + m];
    if (start[t]) { sr = b; si = 0.0; }
    else {
      double nsr = gre * sr - gim * si + b;
      si = gre * si + gim * sr; sr = nsr;
    }
    z[(long)t * 2048 + ch]        = f2bf((float)sr);
    z[(long)t * 2048 + 1024 + ch] = f2bf((float)si);
    aR += sr; aI += si; aS += sr * sr + si * si;
  }
#pragma unroll
  for (int off = 32; off > 0; off >>= 1) {
    aR += __shfl_down(aR, off); aI += __shfl_down(aI, off); aS += __shfl_down(aS, off);
  }
  if ((threadIdx.x & 63) == 0) {
    int w = threadIdx.x >> 6;
    sbuf[w * 3] = aR; sbuf[w * 3 + 1] = aI; sbuf[w * 3 + 2] = aS;
  }
  __syncthreads();
  if (threadIdx.x == 0) {
    atomicAdd(&red[0], sbuf[0] + sbuf[3] + sbuf[6] + sbuf[9]);
    atomicAdd(&red[1], sbuf[1] + sbuf[4] + sbuf[7] + sbuf[10]);
    atomicAdd(&red[2], sbuf[2] + sbuf[5] + sbuf[8] + sbuf[11]);
  }
}

__global__ void finalize_red(const double* __restrict__ red, float* __restrict__ redf) {
  const double n = (double)T_ * (double)MC;
  double mre = red[0] / n, mim = red[1] / n;
  double var = red[2] / n - mre * mre - mim * mim;
  double sd = sqrt(var > 0.0 ? var : 0.0);
  redf[0] = (float)mre;
  redf[1] = (float)mim;
  redf[2] = (float)(1.0 / (1e-6 + sd));
}

// ---------------- bf16 MFMA GEMM: BM=BN=128, A direct-to-registers, B-only LDS (4x8KB) ----------------
// A-fragment per lane is contiguous 16B: A[row][kt+kq..+8] -> global_load_dwordx4, ping-pong regs.
// LDS = 32KB -> 5 blocks/CU cap. Single barrier per K-step (4 B-buffers, depth-2 stage: race-free).
// vmcnt ladder: per iter issues 2 B-stage + 4 A-reg loads; steady vmcnt(6), tail 4/0.
// EP: 1 = plain bf16, 2 = mish bf16, 3 = bf16-add + bf16 out, 4 = scaled affine (z-norm fold) + mish bf16
#define TSZ (128 * 32)
template<int EP>
__device__ __forceinline__ void gemm128_core(const unsigned short* __restrict__ A,
                                             const unsigned short* __restrict__ B,
                                             const float* __restrict__ bias,
                                             const unsigned short* __restrict__ addb,
                                             const float* __restrict__ redf,
                                             const float* __restrict__ wre,
                                             const float* __restrict__ wim,
                                             void* __restrict__ Cout,
                                             int bx, int by, int N_, int K_,
                                             unsigned short* lB) {
  const int tid = threadIdx.x;
  const int lane = tid & 63;
  const int wv = tid >> 6;
  const int wr = wv >> 1, wc = wv & 1;
  const long brow = (long)bx * 128;
  const long bcol = (long)by * 128;

  f32x4 acc[4][4];
#pragma unroll
  for (int i = 0; i < 4; i++)
#pragma unroll
    for (int j = 0; j < 4; j++)
      acc[i][j] = f32x4{0.f, 0.f, 0.f, 0.f};

  // B staging: 512 chunks of 16B per 8KB tile; thread handles c0=tid, c1=tid+256
  const int c0 = tid, c1 = tid + 256;
  const long br0 = bcol + (c0 >> 2), br1 = bcol + (c1 >> 2);
  const int ko0 = (((c0 & 3) ^ ((c0 >> 3) & 3)) * 8);   // inverse-swizzled source slot
  const int ko1 = (((c1 & 3) ^ ((c1 >> 3) & 3)) * 8);
  const int r15 = lane & 15;
  const int kq = (lane >> 4) * 8;
  const int swzq = (((lane >> 4) ^ ((r15 >> 1) & 3)) * 8);

  // A direct: lane's fragment base for row-block mi: Abase + mi*16*K_ + i*32
  const unsigned short* Abase = A + (brow + wr * 64 + r15) * (long)K_ + kq;

  const int nt = K_ >> 5;   // K tiles of 32; nt >= 2 at all call sites

#define STAGE_B(ti, bu)                                                    \
  do {                                                                     \
    gload_lds16(B + br0 * K_ + (ti) * 32 + ko0, lB + (bu) * TSZ + c0 * 8); \
    gload_lds16(B + br1 * K_ + (ti) * 32 + ko1, lB + (bu) * TSZ + c1 * 8); \
  } while (0)

  bf16x8 aCur[4], aNxt[4];
  // prologue: 2 B tiles + A tile 0 in flight
  STAGE_B(0, 0);
  STAGE_B(1, 1);
#pragma unroll
  for (int mi = 0; mi < 4; mi++)
    aCur[mi] = *(const bf16x8*)(Abase + (long)mi * 16 * K_);

  for (int i = 0; i < nt; ++i) {
    if (i + 2 < nt) STAGE_B(i + 2, (i + 2) & 3);
    if (i + 1 < nt) {
#pragma unroll
      for (int mi = 0; mi < 4; mi++)
        aNxt[mi] = *(const bf16x8*)(Abase + (long)mi * 16 * K_ + (i + 1) * 32);
    }
    if (i + 2 < nt)      asm volatile("s_waitcnt vmcnt(6)" ::: "memory");  // B(i)+A(i) landed
    else if (i + 1 < nt) asm volatile("s_waitcnt vmcnt(4)" ::: "memory");
    else                 asm volatile("s_waitcnt vmcnt(0)" ::: "memory");
    __builtin_amdgcn_sched_barrier(0);
    __builtin_amdgcn_s_barrier();           // B tile i visible to all waves; ONLY barrier per K-step
    __builtin_amdgcn_sched_barrier(0);

    const unsigned short* bB = lB + (i & 3) * TSZ;
    bf16x8 bv[4];
#pragma unroll
    for (int nj = 0; nj < 4; nj++)
      bv[nj] = *(const bf16x8*)&bB[(wc * 64 + nj * 16 + r15) * 32 + swzq];
    __builtin_amdgcn_s_setprio(1);
#pragma unroll
    for (int mi = 0; mi < 4; mi++)
#pragma unroll
      for (int nj = 0; nj < 4; nj++)
        acc[mi][nj] = __builtin_amdgcn_mfma_f32_16x16x32_bf16(aCur[mi], bv[nj], acc[mi][nj], 0, 0, 0);
    __builtin_amdgcn_s_setprio(0);
#pragma unroll
    for (int mi = 0; mi < 4; mi++)
      aCur[mi] = aNxt[mi];
  }
#undef STAGE_B

  float cre = 0.f, cim = 0.f, inv = 1.f;
  if (EP == 4) { cre = redf[0]; cim = redf[1]; inv = redf[2]; }

  const int rq = (lane >> 4) * 4;
#pragma unroll
  for (int nj = 0; nj < 4; nj++) {
    const long col = bcol + wc * 64 + nj * 16 + r15;
    const float bs = bias[col];
    float wrc = 0.f, wic = 0.f;
    if (EP == 4) { wrc = wre[col]; wic = wim[col]; }
#pragma unroll
    for (int mi = 0; mi < 4; mi++) {
#pragma unroll
      for (int r = 0; r < 4; r++) {
        const long row = brow + wr * 64 + mi * 16 + rq + r;
        float va = acc[mi][nj][r];
        if (EP == 1) {
          ((unsigned short*)Cout)[row * N_ + col] = f2bf(va + bs);
        } else if (EP == 3) {
          float v = va + bs + bf2f(addb[row * N_ + col]);
          ((unsigned short*)Cout)[row * N_ + col] = f2bf(v);
        } else if (EP == 4) {
          float v = (va - cre * wrc - cim * wic) * inv + bs;
          ((unsigned short*)Cout)[row * N_ + col] = f2bf(mish_f(v));
        } else {
          ((unsigned short*)Cout)[row * N_ + col] = f2bf(mish_f(va + bs));
        }
      }
    }
  }
}

// 2D grid, DEFAULT block mapping (b mod 8 = bx mod 8 keeps A-panel sharers co-XCD)
template<int EP>
__global__ __launch_bounds__(256) void gemm128_k(const unsigned short* __restrict__ A,
                                                 const unsigned short* __restrict__ B,
                                                 const float* __restrict__ bias,
                                                 const unsigned short* __restrict__ addb,
                                                 void* __restrict__ Cout, int N_, int K_) {
  __shared__ __align__(16) unsigned short lB[4 * TSZ];
  gemm128_core<EP>(A, B, bias, addb, nullptr, nullptr, nullptr, Cout,
                   blockIdx.x, blockIdx.y, N_, K_, lB);
}

// merged dispatch, identity mapping: blocks [0,512) = mix1, [512,1024) = skip
__global__ __launch_bounds__(256) void gemm_dual128(const unsigned short* __restrict__ A1,
                                                    const unsigned short* __restrict__ B1,
                                                    const float* __restrict__ bias1,
                                                    unsigned short* __restrict__ C1, int K1,
                                                    const float* __restrict__ redf,
                                                    const float* __restrict__ wre,
                                                    const float* __restrict__ wim,
                                                    const unsigned short* __restrict__ A2,
                                                    const unsigned short* __restrict__ B2,
                                                    const float* __restrict__ bias2,
                                                    unsigned short* __restrict__ C2, int K2) {
  __shared__ __align__(16) unsigned short lB[4 * TSZ];
  int b = blockIdx.x;
  if (b < 512) {
    gemm128_core<4>(A1, B1, bias1, nullptr, redf, wre, wim, C1, b & 63, b >> 6, 1024, K1, lB);
  } else {
    b -= 512;
    gemm128_core<1>(A2, B2, bias2, nullptr, nullptr, nullptr, nullptr, C2, b & 63, b >> 6, 1024, K2, lB);
  }
}

// ---------------- host-side orchestration ----------------
extern "C" void kernel_launch(void* const* d_in, const int* in_sizes, int n_in,
                              void* d_out, int out_size, void* d_ws, size_t ws_size,
                              hipStream_t stream) {
  (void)in_sizes; (void)n_in; (void)ws_size;
  const float* x      = (const float*)d_in[0];
  const float* state0 = (const float*)d_in[1];
  const int*   start  = (const int*)d_in[2];
  const float* a      = (const float*)d_in[4];
  const float* bfr    = (const float*)d_in[5];
  const float* pre_w  = (const float*)d_in[6];
  const float* pre_b  = (const float*)d_in[7];
  const float* skip_w = (const float*)d_in[8];
  const float* skip_b = (const float*)d_in[9];
  const float* w1     = (const float*)d_in[10];
  const float* b1     = (const float*)d_in[11];
  const float* w2     = (const float*)d_in[12];
  const float* b2     = (const float*)d_in[13];
  const float* w3     = (const float*)d_in[14];
  const float* b3     = (const float*)d_in[15];

  char* ws = (char*)d_ws;
  const size_t MB = 1u << 20;
  unsigned short* skipb = (unsigned short*)(ws + 0);         // 16MB bf16 skip out
  float*          part  = (float*)(ws + 16 * MB);            // 16MB [8][T][64]; dead after pre_fin_k
  unsigned short* h3b   = (unsigned short*)(ws + 48 * MB);   // 16MB bf16 mix3 out (+skip)
  unsigned short* z     = (unsigned short*)(ws + 64 * MB);   // 32MB raw bf16 s (re|im)
  unsigned short* xb    = (unsigned short*)(ws + 96 * MB);   // reused as h2 after skip GEMM
  unsigned short* h2    = (unsigned short*)(ws + 96 * MB);
  unsigned short* h1    = (unsigned short*)(ws + 112 * MB);
  unsigned short* wb1   = (unsigned short*)(ws + 128 * MB);
  unsigned short* wb2   = (unsigned short*)(ws + 132 * MB);
  unsigned short* wb3   = (unsigned short*)(ws + 134 * MB);
  unsigned short* skwb  = (unsigned short*)(ws + 136 * MB);
  float*          pre   = (float*)(ws + 138 * MB);
  double2*        chA   = (double2*)(ws + 140 * MB);
  double2*        chB   = (double2*)(ws + 142 * MB);
  double2*        carry = (double2*)(ws + 144 * MB);
  double*         red   = (double*)(ws + 146 * MB);
  float*          redf  = (float*)(ws + 146 * MB + 64);
  float2*         rowst = (float2*)(ws + 147 * MB);          // 64KB [T]
  float*          wre   = (float*)(ws + 147 * MB + 65536);   // 4KB
  float*          wim   = (float*)(ws + 147 * MB + 65536 + 4096);

  // 1) merged prep: weight casts + w1 row sums + LN stats + bf16(x)
  prep_k<<<14336, 256, 0, stream>>>(w1, w2, w3, skip_w, x,
                                    wb1, wb2, wb3, skwb, wre, wim, rowst, xb);

  // 2) exact-f32 pre-projection (K-split, 512 blocks)
  pre_part_k<<<dim3(64, 8), 256, 0, stream>>>(x, rowst, pre_w, part);
  pre_fin_k<<<2048, 256, 0, stream>>>(part, pre_b, pre);

  // 3) chunked scan; p2 writes carry + final-state tail; p3 writes raw z + reduction
  int tail_elems = out_size - T_ * NOUT;          // 1024 (real only) or 2048 (interleaved)
  float* out_tail = (float*)d_out + (long)T_ * NOUT;
  scan_p1<<<dim3(NCH, 4), 256, 0, stream>>>(pre, start, a, bfr, chA, chB);
  scan_p2<<<16, 64, 0, stream>>>(chA, chB, state0, carry, red, out_tail, tail_elems);
  scan_p3<<<dim3(NCH, 4), 256, 0, stream>>>(pre, start, a, bfr, carry, red, z);
  finalize_red<<<1, 1, 0, stream>>>(red, redf);

  // 4) merged mix1(+z-norm fold)+skip, then mix2, mix3(+bf16 skip add)
  gemm_dual128<<<1024, 256, 0, stream>>>(z, wb1, b1, h1, 2048, redf, wre, wim,
                                         xb, skwb, skip_b, skipb, 1024);
  gemm128_k<2><<<dim3(64, 8), 256, 0, stream>>>(h1, wb2, b2, nullptr, h2, 1024, 1024);
  gemm128_k<3><<<dim3(64, 8), 256, 0, stream>>>(h2, wb3, b3, skipb, h3b, 1024, 1024);

  // 5) out = LN(h3)  (h3 already includes skip)
  ln_out1b_k<<<8192, 256, 0, stream>>>(h3b, (float*)d_out);
}

// Round 17
// 256.867 us; speedup vs baseline: 1.3382x; 1.3382x over previous
//
#include <hip/hip_runtime.h>
#include <hip/hip_bf16.h>

// ---------------- problem constants ----------------
#define T_    8192
#define INDIM 1024
#define MTR   64
#define CCTX  16
#define MC    1024     // MTR*CCTX
#define NOUT  1024
#define CHUNK 64
#define NCH   128      // T_/CHUNK

using bf16x8 = __attribute__((ext_vector_type(8))) short;
using f32x4  = __attribute__((ext_vector_type(4))) float;

__device__ __forceinline__ unsigned short f2bf(float f) {
  unsigned int u = __builtin_bit_cast(unsigned int, f);
  u += 0x7fffu + ((u >> 16) & 1u);
  return (unsigned short)(u >> 16);
}
__device__ __forceinline__ float bf2f(unsigned short u) {
  return __builtin_bit_cast(float, (unsigned int)u << 16);
}

// cheap mish: v * tanh(softplus(v)) = v * w/(w+2), w = e^v*(e^v+2); v>20 -> v
__device__ __forceinline__ float mish_f(float v) {
  float u = __expf(v);
  float w = u * (u + 2.f);
  return (v > 20.f) ? v : v * __fdividef(w, w + 2.f);
}

typedef __attribute__((address_space(1))) void gas_void;
typedef __attribute__((address_space(3))) void las_void;

__device__ __forceinline__ void gload_lds16(const void* g, void* l) {
  __builtin_amdgcn_global_load_lds((gas_void*)g, (las_void*)l, 16, 0, 0);
}

__device__ __forceinline__ float2 block_sum2(float s, float ss, float* sbuf) {
#pragma unroll
  for (int off = 32; off > 0; off >>= 1) {
    s  += __shfl_down(s, off);
    ss += __shfl_down(ss, off);
  }
  if ((threadIdx.x & 63) == 0) {
    sbuf[(threadIdx.x >> 6) * 2]     = s;
    sbuf[(threadIdx.x >> 6) * 2 + 1] = ss;
  }
  __syncthreads();
  return make_float2(sbuf[0] + sbuf[2] + sbuf[4] + sbuf[6],
                     sbuf[1] + sbuf[3] + sbuf[5] + sbuf[7]);
}

// ---------------- merged prep: weight casts | w1 row sums | LN stats + x cast ----------------
__global__ __launch_bounds__(256) void prep_k(const float* __restrict__ w1, const float* __restrict__ w2,
                                              const float* __restrict__ w3, const float* __restrict__ sw,
                                              const float* __restrict__ x,
                                              unsigned short* __restrict__ o1, unsigned short* __restrict__ o2,
                                              unsigned short* __restrict__ o3, unsigned short* __restrict__ o4,
                                              float* __restrict__ wre, float* __restrict__ wim,
                                              float2* __restrict__ rowstat, unsigned short* __restrict__ xb) {
  __shared__ float sbuf[8];
  const int b = blockIdx.x;
  if (b < 5120) {
    long i = ((long)b * 256 + threadIdx.x) * 4;
    const float* src; unsigned short* dst; long off;
    if (i < 2097152)      { src = w1; dst = o1; off = i; }
    else if (i < 3145728) { src = w2; dst = o2; off = i - 2097152; }
    else if (i < 4194304) { src = w3; dst = o3; off = i - 3145728; }
    else if (i < 5242880) { src = sw; dst = o4; off = i - 4194304; }
    else return;
    float4 v = *(const float4*)(src + off);
    ushort4 o = { f2bf(v.x), f2bf(v.y), f2bf(v.z), f2bf(v.w) };
    *(ushort4*)(dst + off) = o;
  } else if (b < 6144) {
    const long row = b - 5120;
    const float4* r4 = (const float4*)(w1 + row * 2048);
    float4 a = r4[threadIdx.x];
    float4 c = r4[256 + threadIdx.x];
    float2 t = block_sum2(a.x + a.y + a.z + a.w, c.x + c.y + c.z + c.w, sbuf);
    if (threadIdx.x == 0) { wre[row] = t.x; wim[row] = t.y; }
  } else {
    const long row = b - 6144;
    float4 v = ((const float4*)(x + (row << 10)))[threadIdx.x];
    ushort4 c = { f2bf(v.x), f2bf(v.y), f2bf(v.z), f2bf(v.w) };
    ((ushort4*)(xb + (row << 10)))[threadIdx.x] = c;
    float2 t = block_sum2(v.x + v.y + v.z + v.w,
                          v.x * v.x + v.y * v.y + v.z * v.z + v.w * v.w, sbuf);
    float mean = t.x * (1.f / 1024.f);
    float var  = t.y * (1.f / 1024.f) - mean * mean;
    float rstd = rsqrtf(var + 1e-5f);
    if (threadIdx.x == 0) rowstat[row] = make_float2(mean, rstd);
  }
}

// out = LN(h3) rows of 1024; h3 is bf16
__global__ __launch_bounds__(256) void ln_out1b_k(const unsigned short* __restrict__ p, float* __restrict__ out) {
  __shared__ float sbuf[8];
  const long row = blockIdx.x;
  ushort4 u4 = ((const ushort4*)(p + (row << 10)))[threadIdx.x];
  float4 v = { bf2f(u4.x), bf2f(u4.y), bf2f(u4.z), bf2f(u4.w) };
  float2 t = block_sum2(v.x + v.y + v.z + v.w,
                        v.x * v.x + v.y * v.y + v.z * v.z + v.w * v.w, sbuf);
  float mean = t.x * (1.f / 1024.f);
  float var  = t.y * (1.f / 1024.f) - mean * mean;
  float rstd = rsqrtf(var + 1e-5f);
  float4 o = { (v.x - mean) * rstd, (v.y - mean) * rstd,
               (v.z - mean) * rstd, (v.w - mean) * rstd };
  ((float4*)(out + (row << 10)))[threadIdx.x] = o;
}

// ---------------- f32 pre-projection: register-weights, LN applied algebraically (R12-proven) ----------------
__global__ __launch_bounds__(256) void pre_part_k(const float* __restrict__ x,
                                                  const float2* __restrict__ rowstat,
                                                  const float* __restrict__ pw,
                                                  float* __restrict__ part) {
  const int lane = threadIdx.x & 63;
  const int wvu  = __builtin_amdgcn_readfirstlane(threadIdx.x >> 6);
  const int kc   = blockIdx.y;
  const int r0   = (blockIdx.x * 4 + wvu) * 32;

  const float* wrow = pw + (long)lane * 1024 + kc * 128;
  float wreg[128];
#pragma unroll
  for (int j = 0; j < 32; ++j)
    *(float4*)&wreg[j * 4] = ((const float4*)wrow)[j];
  float swsum = 0.f;
#pragma unroll
  for (int j = 0; j < 128; ++j) swsum += wreg[j];

  float* po = part + ((long)kc * T_ + r0) * 64 + lane;
  const float* xbase = x + (long)r0 * 1024 + kc * 128;

  for (int i = 0; i < 32; i += 2) {
    const float4* xr0 = (const float4*)(xbase + (long)i * 1024);
    const float4* xr1 = (const float4*)(xbase + (long)(i + 1) * 1024);
    float a0 = 0.f, a1 = 0.f, a2 = 0.f, a3 = 0.f;
    float b0 = 0.f, b1 = 0.f, b2 = 0.f, b3 = 0.f;
#pragma unroll
    for (int j = 0; j < 32; j += 4) {
      float4 xa0 = xr0[j],     xa1 = xr0[j + 1], xa2 = xr0[j + 2], xa3 = xr0[j + 3];
      float4 xb0 = xr1[j],     xb1 = xr1[j + 1], xb2 = xr1[j + 2], xb3 = xr1[j + 3];
      a0 += wreg[4*j+0]*xa0.x  + wreg[4*j+1]*xa0.y  + wreg[4*j+2]*xa0.z  + wreg[4*j+3]*xa0.w;
      a1 += wreg[4*j+4]*xa1.x  + wreg[4*j+5]*xa1.y  + wreg[4*j+6]*xa1.z  + wreg[4*j+7]*xa1.w;
      a2 += wreg[4*j+8]*xa2.x  + wreg[4*j+9]*xa2.y  + wreg[4*j+10]*xa2.z + wreg[4*j+11]*xa2.w;
      a3 += wreg[4*j+12]*xa3.x + wreg[4*j+13]*xa3.y + wreg[4*j+14]*xa3.z + wreg[4*j+15]*xa3.w;
      b0 += wreg[4*j+0]*xb0.x  + wreg[4*j+1]*xb0.y  + wreg[4*j+2]*xb0.z  + wreg[4*j+3]*xb0.w;
      b1 += wreg[4*j+4]*xb1.x  + wreg[4*j+5]*xb1.y  + wreg[4*j+6]*xb1.z  + wreg[4*j+7]*xb1.w;
      b2 += wreg[4*j+8]*xb2.x  + wreg[4*j+9]*xb2.y  + wreg[4*j+10]*xb2.z + wreg[4*j+11]*xb2.w;
      b3 += wreg[4*j+12]*xb3.x + wreg[4*j+13]*xb3.y + wreg[4*j+14]*xb3.z + wreg[4*j+15]*xb3.w;
    }
    float2 s0 = rowstat[r0 + i];
    float2 s1 = rowstat[r0 + i + 1];
    po[(long)i * 64]       = s0.y * ((a0 + a1) + (a2 + a3)) - s0.x * s0.y * swsum;
    po[(long)(i + 1) * 64] = s1.y * ((b0 + b1) + (b2 + b3)) - s1.x * s1.y * swsum;
  }
}

// ---------------- fused pre-finalize + chunk scan ----------------
// grid (NCH, 4). Block (j, yq): sums part over kc for slice [64 t][16 m] (m = yq*16+mm),
// applies bias+softplus, writes global pre (for scan_p3), stashes slice in LDS, then scans.
__global__ __launch_bounds__(256) void scan_p1f(const float* __restrict__ part,
                                                const float* __restrict__ pb,
                                                const int* __restrict__ start,
                                                const float* __restrict__ a, const float* __restrict__ bfr,
                                                float* __restrict__ pre,
                                                double2* __restrict__ chA, double2* __restrict__ chB) {
  __shared__ float ps[64][16];
  const int j = blockIdx.x;
  const int yq = blockIdx.y;
  const int t0 = j * CHUNK;
  // phase 1: pre slice
#pragma unroll
  for (int r = 0; r < 4; ++r) {
    int p = threadIdx.x + 256 * r;          // 0..1023
    int tt = p >> 4, mm = p & 15;
    int m = yq * 16 + mm;
    long idx = (long)(t0 + tt) * 64 + m;
    float s = 0.f;
#pragma unroll
    for (int kc = 0; kc < 8; ++kc)
      s += part[(long)kc * T_ * 64 + idx];
    float v = s + pb[m];
    float sp = fmaxf(v, 0.f) + log1pf(expf(-fabsf(v)));
    pre[idx] = sp;
    ps[tt][mm] = sp;
  }
  __syncthreads();
  // phase 2: chunk-local scan for chain ch = yq*256 + tid
  int ch = yq * 256 + threadIdx.x;
  int m = ch >> 4, c = ch & 15;
  int mm = threadIdx.x >> 4;
  double dec = exp(-fabs((double)a[m]));
  double th = (double)bfr[c];
  double gre = dec * cos(th), gim = dec * sin(th);
  double pr = 1.0, pi = 0.0, sr = 0.0, si = 0.0;
  for (int t = 0; t < CHUNK; ++t) {
    double b = (double)ps[t][mm];
    if (start[t0 + t]) {
      pr = 0.0; pi = 0.0; sr = b; si = 0.0;
    } else {
      double nsr = gre * sr - gim * si + b;
      si = gre * si + gim * sr; sr = nsr;
      double npr = gre * pr - gim * pi;
      pi = gre * pi + gim * pr; pr = npr;
    }
  }
  chA[j * MC + ch] = make_double2(pr, pi);
  chB[j * MC + ch] = make_double2(sr, si);
}

// composes chunks (16 blocks x 64 threads); writes carry + final-state tail.
__global__ __launch_bounds__(64) void scan_p2(const double2* __restrict__ chA, const double2* __restrict__ chB,
                                              const float* __restrict__ state0,
                                              double2* __restrict__ carry, double* __restrict__ red,
                                              float* __restrict__ out_tail, int fmt) {
  if (blockIdx.x == 0 && threadIdx.x < 4) red[threadIdx.x] = 0.0;
  int ch = blockIdx.x * 64 + threadIdx.x;
  double cr = (double)state0[ch], ci = 0.0;
  for (int j = 0; j < NCH; ++j) {
    carry[j * MC + ch] = make_double2(cr, ci);
    double2 A = chA[j * MC + ch];
    double2 B = chB[j * MC + ch];
    double ncr = A.x * cr - A.y * ci + B.x;
    ci = A.x * ci + A.y * cr + B.y;
    cr = ncr;
  }
  if (fmt == 1024) {
    out_tail[ch] = (float)cr;
  } else {
    out_tail[2 * ch]     = (float)cr;
    out_tail[2 * ch + 1] = (float)ci;
  }
}

// replay: reduction + RAW bf16 z write (normalization folded into mix1 epilogue)
__global__ __launch_bounds__(256) void scan_p3(const float* __restrict__ pre, const int* __restrict__ start,
                                               const float* __restrict__ a, const float* __restrict__ bfr,
                                               const double2* __restrict__ carry,
                                               double* __restrict__ red,
                                               unsigned short* __restrict__ z) {
  __shared__ double sbuf[12];
  int ch = blockIdx.y * 256 + threadIdx.x;
  int m = ch >> 4, c = ch & 15;
  double dec = exp(-fabs((double)a[m]));
  double th = (double)bfr[c];
  double gre = dec * cos(th), gim = dec * sin(th);
  int j = blockIdx.x;
  int t0 = j * CHUNK;
  double2 cin = carry[j * MC + ch];
  double sr = cin.x, si = cin.y;
  double aR = 0.0, aI = 0.0, aS = 0.0;
  for (int t = t0; t < t0 + CHUNK; ++t) {
    double b = (double)pre[(long)t * 64 + m];
    if (start[t]) { sr = b; si = 0.0; }
    else {
      double nsr = gre * sr - gim * si + b;
      si = gre * si + gim * sr; sr = nsr;
    }
    z[(long)t * 2048 + ch]        = f2bf((float)sr);
    z[(long)t * 2048 + 1024 + ch] = f2bf((float)si);
    aR += sr; aI += si; aS += sr * sr + si * si;
  }
#pragma unroll
  for (int off = 32; off > 0; off >>= 1) {
    aR += __shfl_down(aR, off); aI += __shfl_down(aI, off); aS += __shfl_down(aS, off);
  }
  if ((threadIdx.x & 63) == 0) {
    int w = threadIdx.x >> 6;
    sbuf[w * 3] = aR; sbuf[w * 3 + 1] = aI; sbuf[w * 3 + 2] = aS;
  }
  __syncthreads();
  if (threadIdx.x == 0) {
    atomicAdd(&red[0], sbuf[0] + sbuf[3] + sbuf[6] + sbuf[9]);
    atomicAdd(&red[1], sbuf[1] + sbuf[4] + sbuf[7] + sbuf[10]);
    atomicAdd(&red[2], sbuf[2] + sbuf[5] + sbuf[8] + sbuf[11]);
  }
}

// ---------------- bf16 MFMA GEMM: BM=BN=128, 4-buffer depth-2, single barrier, setprio (R15-proven) ----------------
// EP: 1 = plain bf16, 2 = mish bf16, 3 = bf16-add + bf16 out, 4 = scaled affine (z-norm fold, raw red) + mish bf16
#define TSZ (128 * 32)
template<int EP>
__device__ __forceinline__ void gemm128_core(const unsigned short* __restrict__ A,
                                             const unsigned short* __restrict__ B,
                                             const float* __restrict__ bias,
                                             const unsigned short* __restrict__ addb,
                                             const double* __restrict__ red,
                                             const float* __restrict__ wre,
                                             const float* __restrict__ wim,
                                             void* __restrict__ Cout,
                                             int bx, int by, int N_, int K_,
                                             unsigned short* lA, unsigned short* lB) {
  const int tid = threadIdx.x;
  const int lane = tid & 63;
  const int wv = tid >> 6;
  const int wr = wv >> 1, wc = wv & 1;
  const long brow = (long)bx * 128;
  const long bcol = (long)by * 128;

  f32x4 acc[4][4];
#pragma unroll
  for (int i = 0; i < 4; i++)
#pragma unroll
    for (int j = 0; j < 4; j++)
      acc[i][j] = f32x4{0.f, 0.f, 0.f, 0.f};

  const int c0 = tid, c1 = tid + 256;
  const long ar0 = brow + (c0 >> 2), ar1 = brow + (c1 >> 2);
  const long br0 = bcol + (c0 >> 2), br1 = bcol + (c1 >> 2);
  const int ko0 = (((c0 & 3) ^ ((c0 >> 3) & 3)) * 8);   // inverse-swizzled source slot
  const int ko1 = (((c1 & 3) ^ ((c1 >> 3) & 3)) * 8);
  const int r15 = lane & 15;
  const int swzq = (((lane >> 4) ^ ((r15 >> 1) & 3)) * 8);

  const int nt = K_ >> 5;   // K tiles of 32; nt >= 2 at all call sites

#define STAGE(ti, bu)                                                      \
  do {                                                                     \
    gload_lds16(A + ar0 * K_ + (ti) * 32 + ko0, lA + (bu) * TSZ + c0 * 8); \
    gload_lds16(A + ar1 * K_ + (ti) * 32 + ko1, lA + (bu) * TSZ + c1 * 8); \
    gload_lds16(B + br0 * K_ + (ti) * 32 + ko0, lB + (bu) * TSZ + c0 * 8); \
    gload_lds16(B + br1 * K_ + (ti) * 32 + ko1, lB + (bu) * TSZ + c1 * 8); \
  } while (0)

  // prologue: 2 tiles in flight
  STAGE(0, 0);
  STAGE(1, 1);

  for (int i = 0; i < nt; ++i) {
    if (i + 2 < nt) {
      STAGE(i + 2, (i + 2) & 3);
      asm volatile("s_waitcnt vmcnt(8)" ::: "memory");    // tile i landed (self)
    } else if (i + 1 < nt) {
      asm volatile("s_waitcnt vmcnt(4)" ::: "memory");
    } else {
      asm volatile("s_waitcnt vmcnt(0)" ::: "memory");
    }
    __builtin_amdgcn_sched_barrier(0);
    __builtin_amdgcn_s_barrier();           // all waves' tile-i loads landed; ONLY barrier per K-step
    __builtin_amdgcn_sched_barrier(0);

    const unsigned short* bA = lA + (i & 3) * TSZ;
    const unsigned short* bB = lB + (i & 3) * TSZ;
    bf16x8 af[4], bv[4];
#pragma unroll
    for (int mi = 0; mi < 4; mi++)
      af[mi] = *(const bf16x8*)&bA[(wr * 64 + mi * 16 + r15) * 32 + swzq];
#pragma unroll
    for (int nj = 0; nj < 4; nj++)
      bv[nj] = *(const bf16x8*)&bB[(wc * 64 + nj * 16 + r15) * 32 + swzq];
    __builtin_amdgcn_s_setprio(1);
#pragma unroll
    for (int mi = 0; mi < 4; mi++)
#pragma unroll
      for (int nj = 0; nj < 4; nj++)
        acc[mi][nj] = __builtin_amdgcn_mfma_f32_16x16x32_bf16(af[mi], bv[nj], acc[mi][nj], 0, 0, 0);
    __builtin_amdgcn_s_setprio(0);
  }
#undef STAGE

  float cre = 0.f, cim = 0.f, inv = 1.f;
  if (EP == 4) {
    const double n = (double)T_ * (double)MC;
    double mre = red[0] / n, mim = red[1] / n;
    double var = red[2] / n - mre * mre - mim * mim;
    double sd = sqrt(var > 0.0 ? var : 0.0);
    cre = (float)mre; cim = (float)mim; inv = (float)(1.0 / (1e-6 + sd));
  }

  const int rq = (lane >> 4) * 4;
#pragma unroll
  for (int nj = 0; nj < 4; nj++) {
    const long col = bcol + wc * 64 + nj * 16 + r15;
    const float bs = bias[col];
    float wrc = 0.f, wic = 0.f;
    if (EP == 4) { wrc = wre[col]; wic = wim[col]; }
#pragma unroll
    for (int mi = 0; mi < 4; mi++) {
#pragma unroll
      for (int r = 0; r < 4; r++) {
        const long row = brow + wr * 64 + mi * 16 + rq + r;
        float va = acc[mi][nj][r];
        if (EP == 1) {
          ((unsigned short*)Cout)[row * N_ + col] = f2bf(va + bs);
        } else if (EP == 3) {
          float v = va + bs + bf2f(addb[row * N_ + col]);
          ((unsigned short*)Cout)[row * N_ + col] = f2bf(v);
        } else if (EP == 4) {
          float v = (va - cre * wrc - cim * wic) * inv + bs;
          ((unsigned short*)Cout)[row * N_ + col] = f2bf(mish_f(v));
        } else {
          ((unsigned short*)Cout)[row * N_ + col] = f2bf(mish_f(va + bs));
        }
      }
    }
  }
}

// 2D grid, DEFAULT block mapping (b mod 8 = bx mod 8 keeps A-panel sharers co-XCD)
template<int EP>
__global__ __launch_bounds__(256) void gemm128_k(const unsigned short* __restrict__ A,
                                                 const unsigned short* __restrict__ B,
                                                 const float* __restrict__ bias,
                                                 const unsigned short* __restrict__ addb,
                                                 void* __restrict__ Cout, int N_, int K_) {
  __shared__ __align__(16) unsigned short lA[4 * TSZ];
  __shared__ __align__(16) unsigned short lB[4 * TSZ];
  gemm128_core<EP>(A, B, bias, addb, nullptr, nullptr, nullptr, Cout,
                   blockIdx.x, blockIdx.y, N_, K_, lA, lB);
}

// merged dispatch, identity mapping: blocks [0,512) = mix1, [512,1024) = skip
__global__ __launch_bounds__(256) void gemm_dual128(const unsigned short* __restrict__ A1,
                                                    const unsigned short* __restrict__ B1,
                                                    const float* __restrict__ bias1,
                                                    unsigned short* __restrict__ C1, int K1,
                                                    const double* __restrict__ red,
                                                    const float* __restrict__ wre,
                                                    const float* __restrict__ wim,
                                                    const unsigned short* __restrict__ A2,
                                                    const unsigned short* __restrict__ B2,
                                                    const float* __restrict__ bias2,
                                                    unsigned short* __restrict__ C2, int K2) {
  __shared__ __align__(16) unsigned short lA[4 * TSZ];
  __shared__ __align__(16) unsigned short lB[4 * TSZ];
  int b = blockIdx.x;
  if (b < 512) {
    gemm128_core<4>(A1, B1, bias1, nullptr, red, wre, wim, C1, b & 63, b >> 6, 1024, K1, lA, lB);
  } else {
    b -= 512;
    gemm128_core<1>(A2, B2, bias2, nullptr, nullptr, nullptr, nullptr, C2, b & 63, b >> 6, 1024, K2, lA, lB);
  }
}

// ---------------- host-side orchestration ----------------
extern "C" void kernel_launch(void* const* d_in, const int* in_sizes, int n_in,
                              void* d_out, int out_size, void* d_ws, size_t ws_size,
                              hipStream_t stream) {
  (void)in_sizes; (void)n_in; (void)ws_size;
  const float* x      = (const float*)d_in[0];
  const float* state0 = (const float*)d_in[1];
  const int*   start  = (const int*)d_in[2];
  const float* a      = (const float*)d_in[4];
  const float* bfr    = (const float*)d_in[5];
  const float* pre_w  = (const float*)d_in[6];
  const float* pre_b  = (const float*)d_in[7];
  const float* skip_w = (const float*)d_in[8];
  const float* skip_b = (const float*)d_in[9];
  const float* w1     = (const float*)d_in[10];
  const float* b1     = (const float*)d_in[11];
  const float* w2     = (const float*)d_in[12];
  const float* b2     = (const float*)d_in[13];
  const float* w3     = (const float*)d_in[14];
  const float* b3     = (const float*)d_in[15];

  char* ws = (char*)d_ws;
  const size_t MB = 1u << 20;
  unsigned short* skipb = (unsigned short*)(ws + 0);         // 16MB bf16 skip out
  float*          part  = (float*)(ws + 16 * MB);            // 16MB [8][T][64]; dead after scan_p1f
  unsigned short* h3b   = (unsigned short*)(ws + 48 * MB);   // 16MB bf16 mix3 out (+skip)
  unsigned short* z     = (unsigned short*)(ws + 64 * MB);   // 32MB raw bf16 s (re|im)
  unsigned short* xb    = (unsigned short*)(ws + 96 * MB);   // reused as h2 after skip GEMM
  unsigned short* h2    = (unsigned short*)(ws + 96 * MB);
  unsigned short* h1    = (unsigned short*)(ws + 112 * MB);
  unsigned short* wb1   = (unsigned short*)(ws + 128 * MB);
  unsigned short* wb2   = (unsigned short*)(ws + 132 * MB);
  unsigned short* wb3   = (unsigned short*)(ws + 134 * MB);
  unsigned short* skwb  = (unsigned short*)(ws + 136 * MB);
  float*          pre   = (float*)(ws + 138 * MB);
  double2*        chA   = (double2*)(ws + 140 * MB);
  double2*        chB   = (double2*)(ws + 142 * MB);
  double2*        carry = (double2*)(ws + 144 * MB);
  double*         red   = (double*)(ws + 146 * MB);
  float2*         rowst = (float2*)(ws + 147 * MB);          // 64KB [T]
  float*          wre   = (float*)(ws + 147 * MB + 65536);   // 4KB
  float*          wim   = (float*)(ws + 147 * MB + 65536 + 4096);

  // 1) merged prep: weight casts + w1 row sums + LN stats + bf16(x)
  prep_k<<<14336, 256, 0, stream>>>(w1, w2, w3, skip_w, x,
                                    wb1, wb2, wb3, skwb, wre, wim, rowst, xb);

  // 2) exact-f32 pre-projection partials (K-split, 512 blocks)
  pre_part_k<<<dim3(64, 8), 256, 0, stream>>>(x, rowst, pre_w, part);

  // 3) fused pre-finalize + chunk scan; p2 writes carry + final-state tail; p3 writes raw z + reduction
  int tail_elems = out_size - T_ * NOUT;          // 1024 (real only) or 2048 (interleaved)
  float* out_tail = (float*)d_out + (long)T_ * NOUT;
  scan_p1f<<<dim3(NCH, 4), 256, 0, stream>>>(part, pre_b, start, a, bfr, pre, chA, chB);
  scan_p2<<<16, 64, 0, stream>>>(chA, chB, state0, carry, red, out_tail, tail_elems);
  scan_p3<<<dim3(NCH, 4), 256, 0, stream>>>(pre, start, a, bfr, carry, red, z);

  // 4) merged mix1(+z-norm fold from raw red)+skip, then mix2, mix3(+bf16 skip add)
  gemm_dual128<<<1024, 256, 0, stream>>>(z, wb1, b1, h1, 2048, red, wre, wim,
                                         xb, skwb, skip_b, skipb, 1024);
  gemm128_k<2><<<dim3(64, 8), 256, 0, stream>>>(h1, wb2, b2, nullptr, h2, 1024, 1024);
  gemm128_k<3><<<dim3(64, 8), 256, 0, stream>>>(h2, wb3, b3, skipb, h3b, 1024, 1024);

  // 5) out = LN(h3)  (h3 already includes skip)
  ln_out1b_k<<<8192, 256, 0, stream>>>(h3b, (float*)d_out);
}